// Round 5
// baseline (191.714 us; speedup 1.0000x reference)
//
#include <hip/hip_runtime.h>
#include <cstdint>

#define DIM   128
#define KNN   16
#define NB    2
#define NQ    8192
#define NPTS  4096
#define KVROWS 16
#define GRID  32
#define NCELL (GRID*GRID)
#define CAP   384

typedef unsigned short ushort_t;
typedef short vshort8 __attribute__((ext_vector_type(8)));
typedef float vfloat4 __attribute__((ext_vector_type(4)));

__device__ __forceinline__ ushort_t bf16_rne(float f) {
    unsigned u = __float_as_uint(f);
    unsigned r = u + 0x7FFFu + ((u >> 16) & 1u);
    return (ushort_t)(r >> 16);
}
__device__ __forceinline__ float bf16_to_f(ushort_t h) {
    return __uint_as_float(((unsigned)h) << 16);
}
__device__ __forceinline__ int cell_of(float x) {
    int c = (int)(x * 32.0f);
    return min(max(c, 0), GRID - 1);
}

// ---------------- W-products: Wk1 = w_ks@g_w1 ; pwc = [pe_w@g_w1 | pe_w] (64x256) ----------------
__global__ __launch_bounds__(128) void wprod_k(
    const float* __restrict__ w_ks, const float* __restrict__ g_w1,
    const float* __restrict__ pe_w,
    float* __restrict__ Wk1, float* __restrict__ pwc)
{
    int f = threadIdx.x; int blk = blockIdx.x;
    if (blk < 128) {
        float acc = 0.f;
        for (int t = 0; t < 128; ++t) acc = fmaf(w_ks[blk*128 + t], g_w1[t*128 + f], acc);
        Wk1[blk*128 + f] = acc;
    } else {
        int r = blk - 128;                      // 0..63
        for (int h = 0; h < 2; ++h) {
            int col = f + h*128;
            float v = 0.f;
            if (r < 33) {
                if (col < 128) {
                    float a = 0.f;
                    for (int t = 0; t < 128; ++t) a = fmaf(pe_w[r*128 + t], g_w1[t*128 + col], a);
                    v = a;
                } else {
                    v = pe_w[r*128 + (col - 128)];
                }
            }
            pwc[r*256 + col] = v;
        }
    }
}

// ---------------- pack f32 [K][ncols] into MFMA B-fragments, single bf16 ----------------
__global__ __launch_bounds__(256) void pack_k(
    const float* __restrict__ src, int K, int ncols, int NT, int KS,
    ushort_t* __restrict__ dst)
{
    int gid = blockIdx.x*256 + threadIdx.x;
    int total = NT*KS*64;
    if (gid >= total) return;
    int lane = gid & 63; int c = gid >> 6;
    int s = c % KS; int n = c / KS;
    int k0 = s*32 + ((lane >> 4) << 3);
    int col = n*16 + (lane & 15);
    vshort8 v;
    #pragma unroll
    for (int i = 0; i < 8; ++i) {
        int k = k0 + i;
        float f = (k < K) ? src[k*ncols + col] : 0.f;
        v[i] = (short)bf16_rne(f);
    }
    *(vshort8*)(dst + gid*8) = v;
}

// ---------------- per-batch global branch ----------------
__global__ __launch_bounds__(256) void prep_global_k(
    const float* __restrict__ lat, const float* __restrict__ w_qs,
    const float* __restrict__ w_kg, const float* __restrict__ w_vg,
    const float* __restrict__ g_w1, const float* __restrict__ g_b1,
    const float* __restrict__ g_w2, const float* __restrict__ pe_b,
    float* __restrict__ c1_out, float* __restrict__ vg_out, float* __restrict__ h2g_out)
{
    __shared__ float qs[NB][DIM];
    __shared__ float hg[NB][DIM];
    __shared__ float h1g[NB][DIM];
    int t = threadIdx.x; int b = t >> 7; int f = t & 127;
    float aq = 0.f, ak = 0.f, av = 0.f;
    for (int c = 0; c < DIM; ++c) {
        float l = lat[b*DIM + c];
        aq = fmaf(l, w_qs[c*DIM + f], aq);
        ak = fmaf(l, w_kg[c*DIM + f], ak);
        av = fmaf(l, w_vg[c*DIM + f], av);
    }
    vg_out[b*DIM + f] = av;
    qs[b][f] = aq + pe_b[f];
    hg[b][f] = aq - ak;
    __syncthreads();
    float acc = g_b1[f], acch = g_b1[f];
    for (int c = 0; c < DIM; ++c) {
        float w = g_w1[c*DIM + f];
        acc  = fmaf(qs[b][c], w, acc);
        acch = fmaf(hg[b][c], w, acch);
    }
    c1_out[b*DIM + f] = acc;
    h1g[b][f] = fmaxf(acch, 0.f);
    __syncthreads();
    float acc2 = 0.f;
    for (int c = 0; c < DIM; ++c) acc2 = fmaf(h1g[b][c], g_w2[c*DIM + f], acc2);
    h2g_out[b*DIM + f] = acc2;
}

// ---------------- K1p = points@Wk1 ; Vp' = points@w_vs + pe_b ----------------
__global__ __launch_bounds__(256) void kv_proj_k(
    const float* __restrict__ points, const float* __restrict__ Wk1,
    const float* __restrict__ w_vs, const float* __restrict__ pe_b,
    float* __restrict__ K1p, float* __restrict__ Vp)
{
    __shared__ __align__(16) float pts[KVROWS*DIM];
    int t = threadIdx.x;
    int r0 = blockIdx.x * KVROWS;
    #pragma unroll
    for (int k = 0; k < KVROWS*DIM/256; ++k) {
        int e = t + k*256;
        pts[e] = points[r0*DIM + e];
    }
    __syncthreads();
    int f = t & 127; int mat = t >> 7;
    const float* W = mat ? w_vs : Wk1;
    float* O = mat ? Vp : K1p;
    float addv = mat ? pe_b[f] : 0.f;
    float acc[KVROWS];
    #pragma unroll
    for (int r = 0; r < KVROWS; ++r) acc[r] = 0.f;
    const float4* pts4 = reinterpret_cast<const float4*>(pts);
    for (int c4 = 0; c4 < DIM/4; ++c4) {
        float w0 = W[(c4*4+0)*DIM + f];
        float w1 = W[(c4*4+1)*DIM + f];
        float w2 = W[(c4*4+2)*DIM + f];
        float w3 = W[(c4*4+3)*DIM + f];
        #pragma unroll
        for (int r = 0; r < KVROWS; ++r) {
            float4 p = pts4[r*(DIM/4) + c4];
            acc[r] = fmaf(p.x, w0, acc[r]);
            acc[r] = fmaf(p.y, w1, acc[r]);
            acc[r] = fmaf(p.z, w2, acc[r]);
            acc[r] = fmaf(p.w, w3, acc[r]);
        }
    }
    #pragma unroll
    for (int r = 0; r < KVROWS; ++r) O[(r0 + r)*DIM + f] = acc[r] + addv;
}

// ---------------- spatial binning: count / scan / scatter ----------------
__global__ __launch_bounds__(256) void cellcount_k(
    const float* __restrict__ xyz, int* __restrict__ cnt)
{
    int gid = blockIdx.x*256 + threadIdx.x;
    int b = gid >> 12; int n = gid & (NPTS - 1);
    const float* p = xyz + (b*NPTS + n)*3;
    int cx = cell_of(p[0]);
    int cy = cell_of(p[1]);
    atomicAdd(&cnt[b*NCELL + cy*GRID + cx], 1);
}

__global__ __launch_bounds__(1024) void prefix_k(
    const int* __restrict__ cnt, int* __restrict__ cell_start,
    int* __restrict__ cursor)
{
    __shared__ int s[NCELL];
    int b = blockIdx.x; int t = threadIdx.x;
    int v = cnt[b*NCELL + t];
    s[t] = v;
    __syncthreads();
    for (int off = 1; off < NCELL; off <<= 1) {
        int add = (t >= off) ? s[t - off] : 0;
        __syncthreads();
        s[t] += add;
        __syncthreads();
    }
    int incl = s[t];
    cell_start[b*(NCELL+1) + t] = incl - v;
    cursor[b*NCELL + t] = incl - v;
    if (t == NCELL - 1) cell_start[b*(NCELL+1) + NCELL] = incl;
}

__global__ __launch_bounds__(256) void scatter_k(
    const float* __restrict__ xyz, int* __restrict__ cursor,
    float2* __restrict__ sxy, int* __restrict__ sidx)
{
    int gid = blockIdx.x*256 + threadIdx.x;
    int b = gid >> 12; int n = gid & (NPTS - 1);
    const float* p = xyz + (b*NPTS + n)*3;
    float x = p[0], y = p[1];
    int cx = cell_of(x);
    int cy = cell_of(y);
    int slot = atomicAdd(&cursor[b*NCELL + cy*GRID + cx], 1);
    sxy[b*NPTS + slot] = make_float2(x, y);
    sidx[b*NPTS + slot] = n;
}

// ---------------- exact kNN: grid-binned candidates + 16x wave-argmin ----------------
__global__ __launch_bounds__(256) void knn_k(
    const float* __restrict__ xyz_q, const float2* __restrict__ sxy,
    const int* __restrict__ sidx, const int* __restrict__ cstart,
    int* __restrict__ knn_out)
{
    __shared__ float cand_d[4][CAP];
    __shared__ int   cand_i[4][CAP];
    int t = threadIdx.x; int wid = t >> 6, lane = t & 63;
    int bx = blockIdx.x; int b = bx >> 11; int q = (bx & 2047)*4 + wid;
    float xq = xyz_q[(b*NQ + q)*2 + 0];
    float yq = xyz_q[(b*NQ + q)*2 + 1];
    int cx = cell_of(xq), cy = cell_of(yq);
    const int* cs_b = cstart + b*(NCELL+1);
    float* cd = cand_d[wid]; int* ci = cand_i[wid];
    const float INF = 3.4e38f;
    const float CS = 1.0f/32.0f;
    int* outp = knn_out + (b*NQ + q)*KNN;
    int myIdx = 0;

    for (int R = 2; R < 9; ++R) {
        int x0 = max(cx-R, 0), x1 = min(cx+R, GRID-1);
        int y0 = max(cy-R, 0), y1 = min(cy+R, GRID-1);
        int cnt = 0;
        for (int ry = y0; ry <= y1; ++ry) {
            int s0 = cs_b[ry*GRID + x0];
            int e0 = cs_b[ry*GRID + x1 + 1];
            for (int o = s0 + lane; o < e0; o += 64) {
                float2 p = sxy[b*NPTS + o];
                float dx = __fadd_rn(xq, -p.x);
                float dy = __fadd_rn(yq, -p.y);
                float d = __fadd_rn(__fmul_rn(dx, dx), __fmul_rn(dy, dy));
                int slot = cnt + (o - s0);
                if (slot < CAP) { cd[slot] = d; ci[slot] = o; }
            }
            cnt += e0 - s0;
        }
        asm volatile("s_waitcnt lgkmcnt(0)" ::: "memory");
        __builtin_amdgcn_sched_barrier(0);

        float dr[6];
        #pragma unroll
        for (int k = 0; k < 6; ++k)
            dr[k] = (lane + k*64 < cnt) ? cd[lane + k*64] : INF;
        float d16 = INF;
        for (int r = 0; r < KNN; ++r) {
            float v = dr[0]; int s = lane;
            #pragma unroll
            for (int k = 1; k < 6; ++k)
                if (dr[k] < v) { v = dr[k]; s = lane + k*64; }
            #pragma unroll
            for (int off = 32; off >= 1; off >>= 1) {
                float ov = __shfl_xor(v, off);
                int   os = __shfl_xor(s, off);
                if (ov < v || (ov == v && os < s)) { v = ov; s = os; }
            }
            if (lane == r) myIdx = sidx[b*NPTS + ci[s]];
            if ((s & 63) == lane) {
                int k = s >> 6;
                if      (k == 0) dr[0] = INF;
                else if (k == 1) dr[1] = INF;
                else if (k == 2) dr[2] = INF;
                else if (k == 3) dr[3] = INF;
                else if (k == 4) dr[4] = INF;
                else             dr[5] = INF;
            }
            d16 = v;
        }
        float bl = (x0 > 0)      ? (xq - (float)x0*CS)       : INF;
        float br = (x1 < GRID-1) ? ((float)(x1+1)*CS - xq)   : INF;
        float bb = (y0 > 0)      ? (yq - (float)y0*CS)       : INF;
        float bt = (y1 < GRID-1) ? ((float)(y1+1)*CS - yq)   : INF;
        float safe = fminf(fminf(bl, br), fminf(bb, bt)) - 2e-6f;
        bool whole = (safe > 1e8f);
        bool ok = (cnt >= KNN) && (cnt <= CAP) && (whole || d16 <= safe*safe);
        if (ok || R == 8) {
            if (lane < KNN) outp[lane] = myIdx;
            break;
        }
    }
}

// ---------------- fused MFMA kernel v4: 80 KB LDS (2 blocks/CU), 32 q/block, single-bf16 h1 ----------------
__global__ __launch_bounds__(512, 4) void fuse_k(
    const float* __restrict__ xyz_q, const float* __restrict__ xyz,
    const float* __restrict__ K1p, const float* __restrict__ Vp,
    const int* __restrict__ knn_idx,
    const float* __restrict__ c1_, const float* __restrict__ vg_,
    const float* __restrict__ h2g_, const float* __restrict__ pw32_,
    const ushort_t* __restrict__ pwf, const ushort_t* __restrict__ w2f,
    float* __restrict__ out)
{
    __shared__ __align__(16) ushort_t pwB[16*512];   // 16 KB
    __shared__ __align__(16) ushort_t w2B[32*512];   // 32 KB
    __shared__ __align__(16) ushort_t h1b[8][2048];  // 32 KB (single bf16, per-wave)

    int t = threadIdx.x, lane = t & 63, wid = t >> 6;
    int bx = blockIdx.x; int b = bx >> 8; int qbase = (bx & 255) * 32;

    {   // stage weights once per block (48 KB)
        const int4* s1 = (const int4*)pwf;  int4* d1 = (int4*)pwB;
        #pragma unroll
        for (int i = 0; i < 2; ++i) d1[t + i*512] = s1[t + i*512];
        const int4* s2 = (const int4*)w2f;  int4* d2 = (int4*)w2B;
        #pragma unroll
        for (int i = 0; i < 4; ++i) d2[t + i*512] = s2[t + i*512];
    }
    __syncthreads();

    int c16 = lane & 15, g = lane >> 4, rowbase = g*4;
    ushort_t* hb = h1b[wid];
    const vshort8* pwBv = (const vshort8*)pwB;
    const vshort8* w2Bv = (const vshort8*)w2B;

    // query-invariant hoists (per-lane)
    float pw32r[16], c1r[8];
    #pragma unroll
    for (int n = 0; n < 16; ++n) pw32r[n] = pw32_[n*16 + c16];
    #pragma unroll
    for (int n = 0; n < 8; ++n) c1r[n] = c1_[b*128 + n*16 + c16];

    #pragma unroll 1
    for (int qi = 0; qi < 4; ++qi) {
        int q = qbase + wid*4 + qi;
        float xq = xyz_q[(b*NQ + q)*2 + 0];
        float yq = xyz_q[(b*NQ + q)*2 + 1];
        int idxrow = knn_idx[(b*NQ + q)*KNN + c16];
        const float* p = xyz + (b*NPTS + idxrow)*3;
        float pd0 = xq - p[0], pd1 = yq - p[1], pd2 = p[2];
        int idxr[4];
        #pragma unroll
        for (int r = 0; r < 4; ++r) idxr[r] = __shfl(idxrow, rowbase + r);

        // emb A-fragment in registers: k = g*8 + j
        vshort8 eh;
        int k0 = g*8;
        #pragma unroll
        for (int j = 0; j < 8; ++j) {
            int k = k0 + j;
            float v;
            if (k < 3) {
                v = (k == 0) ? pd0 : (k == 1 ? pd1 : pd2);
            } else {
                int m = k - 3; int fi = m / 6; int rem = m - fi*6;
                int comp = (rem < 3) ? rem : rem - 3;
                float pdc = (comp == 0) ? pd0 : (comp == 1 ? pd1 : pd2);
                float fr = (fi == 0) ? 1.0f : (fi == 1) ? 8.75f : (fi == 2) ? 16.5f
                         : (fi == 3) ? 24.25f : 32.0f;
                float arg = pdc * fr;
                v = (rem < 3) ? __sinf(arg) : __cosf(arg);
            }
            eh[j] = (short)bf16_rne(v);
        }
        float c32 = __cosf(32.0f * pd2);
        float c32r[4];
        #pragma unroll
        for (int r = 0; r < 4; ++r) c32r[r] = __shfl(c32, rowbase + r);

        // pe GEMM: [16x32]@[32x256], single bf16
        vfloat4 acc[16];
        #pragma unroll
        for (int n = 0; n < 16; ++n) acc[n] = (vfloat4){0.f, 0.f, 0.f, 0.f};
        #pragma unroll
        for (int n = 0; n < 16; ++n) {
            vshort8 bh = pwBv[n*64 + lane];
            acc[n] = __builtin_amdgcn_mfma_f32_16x16x32_bf16(eh, bh, acc[n], 0, 0, 0);
        }
        // k=32 rank-1 fixup (f32)
        #pragma unroll
        for (int n = 0; n < 16; ++n) {
            float w = pw32r[n];
            #pragma unroll
            for (int r = 0; r < 4; ++r) acc[n][r] = fmaf(c32r[r], w, acc[n][r]);
        }

        // h1 epilogue: h1 = relu(c1 - K1p + pe1) -> single bf16, frag-linear LDS
        #pragma unroll
        for (int r = 0; r < 4; ++r) {
            const float* kp = K1p + ((b*NPTS + idxr[r]) << 7) + c16;
            float k1r[8];
            #pragma unroll
            for (int n = 0; n < 8; ++n) k1r[n] = kp[n*16];
            #pragma unroll
            for (int n = 0; n < 8; ++n) {
                float h = c1r[n] - k1r[n] + acc[n][r];
                h = fmaxf(h, 0.f);
                int col = n*16 + c16;
                int s = col >> 5;
                int lp = ((col >> 3) & 3) << 4;
                int off = s*512 + (lp | (rowbase + r))*8 + (c16 & 7);
                hb[off] = bf16_rne(h);
            }
        }
        asm volatile("s_waitcnt lgkmcnt(0)" ::: "memory");
        __builtin_amdgcn_sched_barrier(0);

        // prefetch Vp gathers (consumed in softmax)
        float vv[4][8];
        #pragma unroll
        for (int r = 0; r < 4; ++r) {
            const float* vp = Vp + ((b*NPTS + idxr[r]) << 7) + c16;
            #pragma unroll
            for (int n = 0; n < 8; ++n) vv[r][n] = vp[n*16];
        }

        // GEMM2: [16x128]@[128x128], single bf16
        vfloat4 acc2[8];
        #pragma unroll
        for (int n = 0; n < 8; ++n) acc2[n] = (vfloat4){0.f, 0.f, 0.f, 0.f};
        #pragma unroll
        for (int s = 0; s < 4; ++s) {
            vshort8 ah = ((const vshort8*)hb)[s*64 + lane];
            #pragma unroll
            for (int n = 0; n < 8; ++n) {
                vshort8 bh = w2Bv[(n*4 + s)*64 + lane];
                acc2[n] = __builtin_amdgcn_mfma_f32_16x16x32_bf16(ah, bh, acc2[n], 0, 0, 0);
            }
        }

        // softmax over 17 slots + weighted sum
        #pragma unroll
        for (int n = 0; n < 8; ++n) {
            float hg = h2g_[b*128 + n*16 + c16];
            vfloat4 a2 = acc2[n];
            float mx = fmaxf(fmaxf(a2[0], a2[1]), fmaxf(a2[2], a2[3]));
            mx = fmaxf(mx, __shfl_xor(mx, 16));
            mx = fmaxf(mx, __shfl_xor(mx, 32));
            mx = fmaxf(mx, hg);
            float sum = 0.f, num = 0.f;
            #pragma unroll
            for (int r = 0; r < 4; ++r) {
                float ev = __expf(a2[r] - mx);
                float v = vv[r][n] + acc[8 + n][r];
                sum += ev;
                num = fmaf(ev, v, num);
            }
            sum += __shfl_xor(sum, 16); sum += __shfl_xor(sum, 32);
            num += __shfl_xor(num, 16); num += __shfl_xor(num, 32);
            float eg = __expf(hg - mx);
            sum += eg;
            num = fmaf(eg, vg_[b*128 + n*16 + c16], num);
            if (g == 0) out[(b*NQ + q)*128 + n*16 + c16] = num / sum;
        }
        asm volatile("s_waitcnt lgkmcnt(0)" ::: "memory");
        __builtin_amdgcn_sched_barrier(0);
    }
}

extern "C" void kernel_launch(void* const* d_in, const int* in_sizes, int n_in,
                              void* d_out, int out_size, void* d_ws, size_t ws_size,
                              hipStream_t stream) {
    const float* xyz_q  = (const float*)d_in[0];
    const float* lat    = (const float*)d_in[1];
    const float* xyz    = (const float*)d_in[2];
    const float* points = (const float*)d_in[3];
    const float* w_qs   = (const float*)d_in[4];
    const float* w_ks   = (const float*)d_in[5];
    const float* w_vs   = (const float*)d_in[6];
    const float* w_kg   = (const float*)d_in[7];
    const float* w_vg   = (const float*)d_in[8];
    const float* g_w1   = (const float*)d_in[9];
    const float* g_b1   = (const float*)d_in[10];
    const float* g_w2   = (const float*)d_in[11];
    const float* g_b2   = (const float*)d_in[12];  // cancels under softmax
    const float* pe_w   = (const float*)d_in[13];
    const float* pe_b   = (const float*)d_in[14];
    float* out = (float*)d_out;
    (void)g_b2;

    float* ws   = (float*)d_ws;
    float* Vp   = ws;                          // 2*4096*128
    float* K1p  = Vp  + NB*NPTS*DIM;           // 2*4096*128
    float* Wk1  = K1p + NB*NPTS*DIM;           // 128*128
    float* pwc  = Wk1 + DIM*DIM;               // 64*256
    float* c1   = pwc + 64*256;                // 256
    float* vg   = c1  + NB*DIM;                // 256
    float* h2g  = vg  + NB*DIM;                // 256
    int*   knn  = (int*)(h2g + NB*DIM);        // 2*8192*16
    ushort_t* pwf = (ushort_t*)(knn + NB*NQ*KNN);   // 16 KB
    ushort_t* w2f = pwf + 16*64*8;                  // 32 KB
    int* cellcnt  = (int*)(w2f + 32*64*8);          // 2*1024
    int* cellstart = cellcnt + NB*NCELL;            // 2*1025
    int* cursor    = cellstart + NB*(NCELL+1);      // 2*1024
    int* sidx      = cursor + NB*NCELL;             // 2*4096
    float2* sxy    = (float2*)(sidx + NB*NPTS);     // 2*4096 float2

    hipMemsetAsync(cellcnt, 0, NB*NCELL*sizeof(int), stream);
    wprod_k<<<192, 128, 0, stream>>>(w_ks, g_w1, pe_w, Wk1, pwc);
    pack_k<<<4, 256, 0, stream>>>(pwc, 32, 256, 16, 1, pwf);
    pack_k<<<8, 256, 0, stream>>>(g_w2, 128, 128, 8, 4, w2f);
    prep_global_k<<<1, 256, 0, stream>>>(lat, w_qs, w_kg, w_vg,
                                         g_w1, g_b1, g_w2, pe_b, c1, vg, h2g);
    cellcount_k<<<NB*NPTS/256, 256, 0, stream>>>(xyz, cellcnt);
    prefix_k<<<NB, 1024, 0, stream>>>(cellcnt, cellstart, cursor);
    scatter_k<<<NB*NPTS/256, 256, 0, stream>>>(xyz, cursor, sxy, sidx);
    kv_proj_k<<<NB*NPTS/KVROWS, 256, 0, stream>>>(points, Wk1, w_vs, pe_b, K1p, Vp);
    knn_k<<<NB*NQ/4, 256, 0, stream>>>(xyz_q, sxy, sidx, cellstart, knn);
    fuse_k<<<NB*NQ/32, 512, 0, stream>>>(xyz_q, xyz, K1p, Vp, knn, c1, vg, h2g,
                                         pwc + 32*256, pwf, w2f, out);
}

// Round 6
// 153.777 us; speedup vs baseline: 1.2467x; 1.2467x over previous
//
#include <hip/hip_runtime.h>
#include <cstdint>

#define DIM   128
#define KNN   16
#define NB    2
#define NQ    8192
#define NPTS  4096
#define KVROWS 16
#define GRID  32
#define NCELL (GRID*GRID)
#define CAP   384

typedef unsigned short ushort_t;
typedef short vshort8 __attribute__((ext_vector_type(8)));
typedef float vfloat4 __attribute__((ext_vector_type(4)));

__device__ __forceinline__ ushort_t bf16_rne(float f) {
    unsigned u = __float_as_uint(f);
    unsigned r = u + 0x7FFFu + ((u >> 16) & 1u);
    return (ushort_t)(r >> 16);
}
__device__ __forceinline__ float bf16_to_f(ushort_t h) {
    return __uint_as_float(((unsigned)h) << 16);
}
__device__ __forceinline__ int cell_of(float x) {
    int c = (int)(x * 32.0f);
    return min(max(c, 0), GRID - 1);
}

// ---------------- W-products: Wk1 = w_ks@g_w1 ; pwc = [pe_w@g_w1 | pe_w] (64x256) ----------------
__global__ __launch_bounds__(128) void wprod_k(
    const float* __restrict__ w_ks, const float* __restrict__ g_w1,
    const float* __restrict__ pe_w,
    float* __restrict__ Wk1, float* __restrict__ pwc)
{
    int f = threadIdx.x; int blk = blockIdx.x;
    if (blk < 128) {
        float acc = 0.f;
        for (int t = 0; t < 128; ++t) acc = fmaf(w_ks[blk*128 + t], g_w1[t*128 + f], acc);
        Wk1[blk*128 + f] = acc;
    } else {
        int r = blk - 128;                      // 0..63
        for (int h = 0; h < 2; ++h) {
            int col = f + h*128;
            float v = 0.f;
            if (r < 33) {
                if (col < 128) {
                    float a = 0.f;
                    for (int t = 0; t < 128; ++t) a = fmaf(pe_w[r*128 + t], g_w1[t*128 + col], a);
                    v = a;
                } else {
                    v = pe_w[r*128 + (col - 128)];
                }
            }
            pwc[r*256 + col] = v;
        }
    }
}

// ---------------- pack f32 [K][ncols] into MFMA B-fragments, single bf16 ----------------
__global__ __launch_bounds__(256) void pack_k(
    const float* __restrict__ src, int K, int ncols, int NT, int KS,
    ushort_t* __restrict__ dst)
{
    int gid = blockIdx.x*256 + threadIdx.x;
    int total = NT*KS*64;
    if (gid >= total) return;
    int lane = gid & 63; int c = gid >> 6;
    int s = c % KS; int n = c / KS;
    int k0 = s*32 + ((lane >> 4) << 3);
    int col = n*16 + (lane & 15);
    vshort8 v;
    #pragma unroll
    for (int i = 0; i < 8; ++i) {
        int k = k0 + i;
        float f = (k < K) ? src[k*ncols + col] : 0.f;
        v[i] = (short)bf16_rne(f);
    }
    *(vshort8*)(dst + gid*8) = v;
}

// ---------------- per-batch global branch ----------------
__global__ __launch_bounds__(256) void prep_global_k(
    const float* __restrict__ lat, const float* __restrict__ w_qs,
    const float* __restrict__ w_kg, const float* __restrict__ w_vg,
    const float* __restrict__ g_w1, const float* __restrict__ g_b1,
    const float* __restrict__ g_w2, const float* __restrict__ pe_b,
    float* __restrict__ c1_out, float* __restrict__ vg_out, float* __restrict__ h2g_out)
{
    __shared__ float qs[NB][DIM];
    __shared__ float hg[NB][DIM];
    __shared__ float h1g[NB][DIM];
    int t = threadIdx.x; int b = t >> 7; int f = t & 127;
    float aq = 0.f, ak = 0.f, av = 0.f;
    for (int c = 0; c < DIM; ++c) {
        float l = lat[b*DIM + c];
        aq = fmaf(l, w_qs[c*DIM + f], aq);
        ak = fmaf(l, w_kg[c*DIM + f], ak);
        av = fmaf(l, w_vg[c*DIM + f], av);
    }
    vg_out[b*DIM + f] = av;
    qs[b][f] = aq + pe_b[f];
    hg[b][f] = aq - ak;
    __syncthreads();
    float acc = g_b1[f], acch = g_b1[f];
    for (int c = 0; c < DIM; ++c) {
        float w = g_w1[c*DIM + f];
        acc  = fmaf(qs[b][c], w, acc);
        acch = fmaf(hg[b][c], w, acch);
    }
    c1_out[b*DIM + f] = acc;
    h1g[b][f] = fmaxf(acch, 0.f);
    __syncthreads();
    float acc2 = 0.f;
    for (int c = 0; c < DIM; ++c) acc2 = fmaf(h1g[b][c], g_w2[c*DIM + f], acc2);
    h2g_out[b*DIM + f] = acc2;
}

// ---------------- K1p = points@Wk1 ; Vp' = points@w_vs + pe_b ----------------
__global__ __launch_bounds__(256) void kv_proj_k(
    const float* __restrict__ points, const float* __restrict__ Wk1,
    const float* __restrict__ w_vs, const float* __restrict__ pe_b,
    float* __restrict__ K1p, float* __restrict__ Vp)
{
    __shared__ __align__(16) float pts[KVROWS*DIM];
    int t = threadIdx.x;
    int r0 = blockIdx.x * KVROWS;
    #pragma unroll
    for (int k = 0; k < KVROWS*DIM/256; ++k) {
        int e = t + k*256;
        pts[e] = points[r0*DIM + e];
    }
    __syncthreads();
    int f = t & 127; int mat = t >> 7;
    const float* W = mat ? w_vs : Wk1;
    float* O = mat ? Vp : K1p;
    float addv = mat ? pe_b[f] : 0.f;
    float acc[KVROWS];
    #pragma unroll
    for (int r = 0; r < KVROWS; ++r) acc[r] = 0.f;
    const float4* pts4 = reinterpret_cast<const float4*>(pts);
    for (int c4 = 0; c4 < DIM/4; ++c4) {
        float w0 = W[(c4*4+0)*DIM + f];
        float w1 = W[(c4*4+1)*DIM + f];
        float w2 = W[(c4*4+2)*DIM + f];
        float w3 = W[(c4*4+3)*DIM + f];
        #pragma unroll
        for (int r = 0; r < KVROWS; ++r) {
            float4 p = pts4[r*(DIM/4) + c4];
            acc[r] = fmaf(p.x, w0, acc[r]);
            acc[r] = fmaf(p.y, w1, acc[r]);
            acc[r] = fmaf(p.z, w2, acc[r]);
            acc[r] = fmaf(p.w, w3, acc[r]);
        }
    }
    #pragma unroll
    for (int r = 0; r < KVROWS; ++r) O[(r0 + r)*DIM + f] = acc[r] + addv;
}

// ---------------- spatial binning: count / scan / scatter ----------------
__global__ __launch_bounds__(256) void cellcount_k(
    const float* __restrict__ xyz, int* __restrict__ cnt)
{
    int gid = blockIdx.x*256 + threadIdx.x;
    int b = gid >> 12; int n = gid & (NPTS - 1);
    const float* p = xyz + (b*NPTS + n)*3;
    int cx = cell_of(p[0]);
    int cy = cell_of(p[1]);
    atomicAdd(&cnt[b*NCELL + cy*GRID + cx], 1);
}

__global__ __launch_bounds__(1024) void prefix_k(
    const int* __restrict__ cnt, int* __restrict__ cell_start,
    int* __restrict__ cursor)
{
    __shared__ int s[NCELL];
    int b = blockIdx.x; int t = threadIdx.x;
    int v = cnt[b*NCELL + t];
    s[t] = v;
    __syncthreads();
    for (int off = 1; off < NCELL; off <<= 1) {
        int add = (t >= off) ? s[t - off] : 0;
        __syncthreads();
        s[t] += add;
        __syncthreads();
    }
    int incl = s[t];
    cell_start[b*(NCELL+1) + t] = incl - v;
    cursor[b*NCELL + t] = incl - v;
    if (t == NCELL - 1) cell_start[b*(NCELL+1) + NCELL] = incl;
}

__global__ __launch_bounds__(256) void scatter_k(
    const float* __restrict__ xyz, int* __restrict__ cursor,
    float2* __restrict__ sxy, int* __restrict__ sidx)
{
    int gid = blockIdx.x*256 + threadIdx.x;
    int b = gid >> 12; int n = gid & (NPTS - 1);
    const float* p = xyz + (b*NPTS + n)*3;
    float x = p[0], y = p[1];
    int cx = cell_of(x);
    int cy = cell_of(y);
    int slot = atomicAdd(&cursor[b*NCELL + cy*GRID + cx], 1);
    sxy[b*NPTS + slot] = make_float2(x, y);
    sidx[b*NPTS + slot] = n;
}

// ---------------- exact kNN: grid-binned candidates + 16x wave-argmin ----------------
__global__ __launch_bounds__(256) void knn_k(
    const float* __restrict__ xyz_q, const float2* __restrict__ sxy,
    const int* __restrict__ sidx, const int* __restrict__ cstart,
    int* __restrict__ knn_out)
{
    __shared__ float cand_d[4][CAP];
    __shared__ int   cand_i[4][CAP];
    int t = threadIdx.x; int wid = t >> 6, lane = t & 63;
    int bx = blockIdx.x; int b = bx >> 11; int q = (bx & 2047)*4 + wid;
    float xq = xyz_q[(b*NQ + q)*2 + 0];
    float yq = xyz_q[(b*NQ + q)*2 + 1];
    int cx = cell_of(xq), cy = cell_of(yq);
    const int* cs_b = cstart + b*(NCELL+1);
    float* cd = cand_d[wid]; int* ci = cand_i[wid];
    const float INF = 3.4e38f;
    const float CS = 1.0f/32.0f;
    int* outp = knn_out + (b*NQ + q)*KNN;
    int myIdx = 0;

    for (int R = 2; R < 9; ++R) {
        int x0 = max(cx-R, 0), x1 = min(cx+R, GRID-1);
        int y0 = max(cy-R, 0), y1 = min(cy+R, GRID-1);
        int cnt = 0;
        for (int ry = y0; ry <= y1; ++ry) {
            int s0 = cs_b[ry*GRID + x0];
            int e0 = cs_b[ry*GRID + x1 + 1];
            for (int o = s0 + lane; o < e0; o += 64) {
                float2 p = sxy[b*NPTS + o];
                float dx = __fadd_rn(xq, -p.x);
                float dy = __fadd_rn(yq, -p.y);
                float d = __fadd_rn(__fmul_rn(dx, dx), __fmul_rn(dy, dy));
                int slot = cnt + (o - s0);
                if (slot < CAP) { cd[slot] = d; ci[slot] = o; }
            }
            cnt += e0 - s0;
        }
        asm volatile("s_waitcnt lgkmcnt(0)" ::: "memory");
        __builtin_amdgcn_sched_barrier(0);

        float dr[6];
        #pragma unroll
        for (int k = 0; k < 6; ++k)
            dr[k] = (lane + k*64 < cnt) ? cd[lane + k*64] : INF;
        float d16 = INF;
        for (int r = 0; r < KNN; ++r) {
            float v = dr[0]; int s = lane;
            #pragma unroll
            for (int k = 1; k < 6; ++k)
                if (dr[k] < v) { v = dr[k]; s = lane + k*64; }
            #pragma unroll
            for (int off = 32; off >= 1; off >>= 1) {
                float ov = __shfl_xor(v, off);
                int   os = __shfl_xor(s, off);
                if (ov < v || (ov == v && os < s)) { v = ov; s = os; }
            }
            if (lane == r) myIdx = sidx[b*NPTS + ci[s]];
            if ((s & 63) == lane) {
                int k = s >> 6;
                if      (k == 0) dr[0] = INF;
                else if (k == 1) dr[1] = INF;
                else if (k == 2) dr[2] = INF;
                else if (k == 3) dr[3] = INF;
                else if (k == 4) dr[4] = INF;
                else             dr[5] = INF;
            }
            d16 = v;
        }
        float bl = (x0 > 0)      ? (xq - (float)x0*CS)       : INF;
        float br = (x1 < GRID-1) ? ((float)(x1+1)*CS - xq)   : INF;
        float bb = (y0 > 0)      ? (yq - (float)y0*CS)       : INF;
        float bt = (y1 < GRID-1) ? ((float)(y1+1)*CS - yq)   : INF;
        float safe = fminf(fminf(bl, br), fminf(bb, bt)) - 2e-6f;
        bool whole = (safe > 1e8f);
        bool ok = (cnt >= KNN) && (cnt <= CAP) && (whole || d16 <= safe*safe);
        if (ok || R == 8) {
            if (lane < KNN) outp[lane] = myIdx;
            break;
        }
    }
}

// ---------------- fused MFMA kernel v6: 80 KB LDS, low-register phase-split ----------------
// 512 threads = 8 waves, 1 query per wave per iteration, 4 iterations (32 q/block).
// No forced VGPR cap (launch_bounds min-waves=2); live-set engineered to stay <=128
// so HW occupancy reaches 4 waves/SIMD (2 blocks/CU via 80 KB LDS).
__global__ __launch_bounds__(512, 2) void fuse_k(
    const float* __restrict__ xyz_q, const float* __restrict__ xyz,
    const float* __restrict__ K1p, const float* __restrict__ Vp,
    const int* __restrict__ knn_idx,
    const float* __restrict__ c1_, const float* __restrict__ vg_,
    const float* __restrict__ h2g_, const float* __restrict__ pw32_,
    const ushort_t* __restrict__ pwf, const ushort_t* __restrict__ w2f,
    float* __restrict__ out)
{
    __shared__ __align__(16) ushort_t pwB[16*512];   // 16 KB
    __shared__ __align__(16) ushort_t w2B[32*512];   // 32 KB
    __shared__ __align__(16) ushort_t h1b[8][2048];  // 32 KB (single bf16, per-wave)

    int t = threadIdx.x, lane = t & 63, wid = t >> 6;
    int bx = blockIdx.x; int b = bx >> 8; int qbase = (bx & 255) * 32;

    {   // stage weights once per block (48 KB)
        const int4* s1 = (const int4*)pwf;  int4* d1 = (int4*)pwB;
        #pragma unroll
        for (int i = 0; i < 2; ++i) d1[t + i*512] = s1[t + i*512];
        const int4* s2 = (const int4*)w2f;  int4* d2 = (int4*)w2B;
        #pragma unroll
        for (int i = 0; i < 4; ++i) d2[t + i*512] = s2[t + i*512];
    }
    __syncthreads();

    int c16 = lane & 15, g = lane >> 4, rowbase = g*4;
    ushort_t* hb = h1b[wid];
    const vshort8* pwBv = (const vshort8*)pwB;
    const vshort8* w2Bv = (const vshort8*)w2B;
    const vfloat4 vzero = (vfloat4){0.f, 0.f, 0.f, 0.f};

    // query-invariant hoists (per-lane): 40 regs
    float pw32r[16], c1r[8], hgr[8], vgr[8];
    #pragma unroll
    for (int n = 0; n < 16; ++n) pw32r[n] = pw32_[n*16 + c16];
    #pragma unroll
    for (int n = 0; n < 8; ++n) {
        c1r[n] = c1_[b*128 + n*16 + c16];
        hgr[n] = h2g_[b*128 + n*16 + c16];
        vgr[n] = vg_[b*128 + n*16 + c16];
    }

    #pragma unroll 1
    for (int qi = 0; qi < 4; ++qi) {
        int q = qbase + wid*4 + qi;
        float xq = xyz_q[(b*NQ + q)*2 + 0];
        float yq = xyz_q[(b*NQ + q)*2 + 1];
        int idxrow = knn_idx[(b*NQ + q)*KNN + c16];
        const float* p = xyz + (b*NPTS + idxrow)*3;
        float pd0 = xq - p[0], pd1 = yq - p[1], pd2 = p[2];
        int idxr[4];
        #pragma unroll
        for (int r = 0; r < 4; ++r) idxr[r] = __shfl(idxrow, rowbase + r);

        // emb A-fragment in registers: k = g*8 + j
        vshort8 eh;
        int k0 = g*8;
        #pragma unroll
        for (int j = 0; j < 8; ++j) {
            int k = k0 + j;
            float v;
            if (k < 3) {
                v = (k == 0) ? pd0 : (k == 1 ? pd1 : pd2);
            } else {
                int m = k - 3; int fi = m / 6; int rem = m - fi*6;
                int comp = (rem < 3) ? rem : rem - 3;
                float pdc = (comp == 0) ? pd0 : (comp == 1 ? pd1 : pd2);
                float fr = (fi == 0) ? 1.0f : (fi == 1) ? 8.75f : (fi == 2) ? 16.5f
                         : (fi == 3) ? 24.25f : 32.0f;
                float arg = pdc * fr;
                v = (rem < 3) ? __sinf(arg) : __cosf(arg);
            }
            eh[j] = (short)bf16_rne(v);
        }
        float c32 = __cosf(32.0f * pd2);
        float c32r[4];
        #pragma unroll
        for (int r = 0; r < 4; ++r) c32r[r] = __shfl(c32, rowbase + r);

        // K1p gather prefetch (transient: dies at end of pe1 phase)
        float k1v[4][8];
        #pragma unroll
        for (int r = 0; r < 4; ++r) {
            const float* kp = K1p + ((b*NPTS + idxr[r]) << 7) + c16;
            #pragma unroll
            for (int n = 0; n < 8; ++n) k1v[r][n] = kp[n*16];
        }

        // pe1 + h1 epilogue, one n at a time (acc1 live = 4 regs)
        #pragma unroll
        for (int n = 0; n < 8; ++n) {
            vfloat4 a = __builtin_amdgcn_mfma_f32_16x16x32_bf16(
                eh, pwBv[n*64 + lane], vzero, 0, 0, 0);
            int col = n*16 + c16;
            int s = col >> 5;
            int lp = ((col >> 3) & 3) << 4;
            int j = c16 & 7;
            #pragma unroll
            for (int r = 0; r < 4; ++r) {
                float h = c1r[n] - k1v[r][n] + fmaf(c32r[r], pw32r[n], a[r]);
                h = fmaxf(h, 0.f);
                hb[s*512 + (lp | (rowbase + r))*8 + j] = bf16_rne(h);
            }
        }
        asm volatile("s_waitcnt lgkmcnt(0)" ::: "memory");
        __builtin_amdgcn_sched_barrier(0);

        // GEMM2: [16x128]@[128x128], single bf16
        vfloat4 acc2[8];
        #pragma unroll
        for (int n = 0; n < 8; ++n) acc2[n] = vzero;
        #pragma unroll
        for (int s = 0; s < 4; ++s) {
            vshort8 ah = ((const vshort8*)hb)[s*64 + lane];
            #pragma unroll
            for (int n = 0; n < 8; ++n) {
                vshort8 bh = w2Bv[(n*4 + s)*64 + lane];
                acc2[n] = __builtin_amdgcn_mfma_f32_16x16x32_bf16(ah, bh, acc2[n], 0, 0, 0);
            }
        }

        // softmax over 17 slots, pe2 computed per-n (accp live = 4 regs),
        // Vp gathers depth-1 pipelined (8 regs)
        const float* vbase[4];
        #pragma unroll
        for (int r = 0; r < 4; ++r) vbase[r] = Vp + ((b*NPTS + idxr[r]) << 7) + c16;
        float vvp[4];
        #pragma unroll
        for (int r = 0; r < 4; ++r) vvp[r] = vbase[r][0];

        #pragma unroll
        for (int n = 0; n < 8; ++n) {
            float vvc[4];
            #pragma unroll
            for (int r = 0; r < 4; ++r) vvc[r] = vvp[r];
            if (n < 7) {
                #pragma unroll
                for (int r = 0; r < 4; ++r) vvp[r] = vbase[r][(n+1)*16];
            }
            vfloat4 ap = __builtin_amdgcn_mfma_f32_16x16x32_bf16(
                eh, pwBv[(8 + n)*64 + lane], vzero, 0, 0, 0);
            #pragma unroll
            for (int r = 0; r < 4; ++r) ap[r] = fmaf(c32r[r], pw32r[8 + n], ap[r]);

            float hg = hgr[n];
            vfloat4 a2 = acc2[n];
            float mx = fmaxf(fmaxf(a2[0], a2[1]), fmaxf(a2[2], a2[3]));
            mx = fmaxf(mx, __shfl_xor(mx, 16));
            mx = fmaxf(mx, __shfl_xor(mx, 32));
            mx = fmaxf(mx, hg);
            float sum = 0.f, num = 0.f;
            #pragma unroll
            for (int r = 0; r < 4; ++r) {
                float ev = __expf(a2[r] - mx);
                float v = vvc[r] + ap[r];
                sum += ev;
                num = fmaf(ev, v, num);
            }
            sum += __shfl_xor(sum, 16); sum += __shfl_xor(sum, 32);
            num += __shfl_xor(num, 16); num += __shfl_xor(num, 32);
            float eg = __expf(hg - mx);
            sum += eg;
            num = fmaf(eg, vgr[n], num);
            if (g == 0) out[(b*NQ + q)*128 + n*16 + c16] = num / sum;
        }
        asm volatile("s_waitcnt lgkmcnt(0)" ::: "memory");
        __builtin_amdgcn_sched_barrier(0);
    }
}

extern "C" void kernel_launch(void* const* d_in, const int* in_sizes, int n_in,
                              void* d_out, int out_size, void* d_ws, size_t ws_size,
                              hipStream_t stream) {
    const float* xyz_q  = (const float*)d_in[0];
    const float* lat    = (const float*)d_in[1];
    const float* xyz    = (const float*)d_in[2];
    const float* points = (const float*)d_in[3];
    const float* w_qs   = (const float*)d_in[4];
    const float* w_ks   = (const float*)d_in[5];
    const float* w_vs   = (const float*)d_in[6];
    const float* w_kg   = (const float*)d_in[7];
    const float* w_vg   = (const float*)d_in[8];
    const float* g_w1   = (const float*)d_in[9];
    const float* g_b1   = (const float*)d_in[10];
    const float* g_w2   = (const float*)d_in[11];
    const float* g_b2   = (const float*)d_in[12];  // cancels under softmax
    const float* pe_w   = (const float*)d_in[13];
    const float* pe_b   = (const float*)d_in[14];
    float* out = (float*)d_out;
    (void)g_b2;

    float* ws   = (float*)d_ws;
    float* Vp   = ws;                          // 2*4096*128
    float* K1p  = Vp  + NB*NPTS*DIM;           // 2*4096*128
    float* Wk1  = K1p + NB*NPTS*DIM;           // 128*128
    float* pwc  = Wk1 + DIM*DIM;               // 64*256
    float* c1   = pwc + 64*256;                // 256
    float* vg   = c1  + NB*DIM;                // 256
    float* h2g  = vg  + NB*DIM;                // 256
    int*   knn  = (int*)(h2g + NB*DIM);        // 2*8192*16
    ushort_t* pwf = (ushort_t*)(knn + NB*NQ*KNN);   // 16 KB
    ushort_t* w2f = pwf + 16*64*8;                  // 32 KB
    int* cellcnt  = (int*)(w2f + 32*64*8);          // 2*1024
    int* cellstart = cellcnt + NB*NCELL;            // 2*1025
    int* cursor    = cellstart + NB*(NCELL+1);      // 2*1024
    int* sidx      = cursor + NB*NCELL;             // 2*4096
    float2* sxy    = (float2*)(sidx + NB*NPTS);     // 2*4096 float2

    hipMemsetAsync(cellcnt, 0, NB*NCELL*sizeof(int), stream);
    wprod_k<<<192, 128, 0, stream>>>(w_ks, g_w1, pe_w, Wk1, pwc);
    pack_k<<<4, 256, 0, stream>>>(pwc, 32, 256, 16, 1, pwf);
    pack_k<<<8, 256, 0, stream>>>(g_w2, 128, 128, 8, 4, w2f);
    prep_global_k<<<1, 256, 0, stream>>>(lat, w_qs, w_kg, w_vg,
                                         g_w1, g_b1, g_w2, pe_b, c1, vg, h2g);
    cellcount_k<<<NB*NPTS/256, 256, 0, stream>>>(xyz, cellcnt);
    prefix_k<<<NB, 1024, 0, stream>>>(cellcnt, cellstart, cursor);
    scatter_k<<<NB*NPTS/256, 256, 0, stream>>>(xyz, cursor, sxy, sidx);
    kv_proj_k<<<NB*NPTS/KVROWS, 256, 0, stream>>>(points, Wk1, w_vs, pe_b, K1p, Vp);
    knn_k<<<NB*NQ/4, 256, 0, stream>>>(xyz_q, sxy, sidx, cellstart, knn);
    fuse_k<<<NB*NQ/32, 512, 0, stream>>>(xyz_q, xyz, K1p, Vp, knn, c1, vg, h2g,
                                         pwc + 32*256, pwf, w2f, out);
}

// Round 7
// 153.012 us; speedup vs baseline: 1.2529x; 1.0050x over previous
//
#include <hip/hip_runtime.h>
#include <cstdint>

#define DIM   128
#define KNN   16
#define NB    2
#define NQ    8192
#define NPTS  4096
#define KVROWS 16
#define GRID  32
#define NCELL (GRID*GRID)
#define CAP   384

typedef unsigned short ushort_t;
typedef short vshort8 __attribute__((ext_vector_type(8)));
typedef float vfloat4 __attribute__((ext_vector_type(4)));

__device__ __forceinline__ ushort_t bf16_rne(float f) {
    unsigned u = __float_as_uint(f);
    unsigned r = u + 0x7FFFu + ((u >> 16) & 1u);
    return (ushort_t)(r >> 16);
}
__device__ __forceinline__ float bf16_to_f(ushort_t h) {
    return __uint_as_float(((unsigned)h) << 16);
}
__device__ __forceinline__ int cell_of(float x) {
    int c = (int)(x * 32.0f);
    return min(max(c, 0), GRID - 1);
}

// ---------------- W-products: Wk1 = w_ks@g_w1 ; pwc = [pe_w@g_w1 | pe_w] (64x256) ----------------
__global__ __launch_bounds__(128) void wprod_k(
    const float* __restrict__ w_ks, const float* __restrict__ g_w1,
    const float* __restrict__ pe_w,
    float* __restrict__ Wk1, float* __restrict__ pwc)
{
    int f = threadIdx.x; int blk = blockIdx.x;
    if (blk < 128) {
        float acc = 0.f;
        for (int t = 0; t < 128; ++t) acc = fmaf(w_ks[blk*128 + t], g_w1[t*128 + f], acc);
        Wk1[blk*128 + f] = acc;
    } else {
        int r = blk - 128;                      // 0..63
        for (int h = 0; h < 2; ++h) {
            int col = f + h*128;
            float v = 0.f;
            if (r < 33) {
                if (col < 128) {
                    float a = 0.f;
                    for (int t = 0; t < 128; ++t) a = fmaf(pe_w[r*128 + t], g_w1[t*128 + col], a);
                    v = a;
                } else {
                    v = pe_w[r*128 + (col - 128)];
                }
            }
            pwc[r*256 + col] = v;
        }
    }
}

// ---------------- pack f32 [K][ncols] into MFMA B-fragments, single bf16 ----------------
__global__ __launch_bounds__(256) void pack_k(
    const float* __restrict__ src, int K, int ncols, int NT, int KS,
    ushort_t* __restrict__ dst)
{
    int gid = blockIdx.x*256 + threadIdx.x;
    int total = NT*KS*64;
    if (gid >= total) return;
    int lane = gid & 63; int c = gid >> 6;
    int s = c % KS; int n = c / KS;
    int k0 = s*32 + ((lane >> 4) << 3);
    int col = n*16 + (lane & 15);
    vshort8 v;
    #pragma unroll
    for (int i = 0; i < 8; ++i) {
        int k = k0 + i;
        float f = (k < K) ? src[k*ncols + col] : 0.f;
        v[i] = (short)bf16_rne(f);
    }
    *(vshort8*)(dst + gid*8) = v;
}

// ---------------- per-batch global branch ----------------
__global__ __launch_bounds__(256) void prep_global_k(
    const float* __restrict__ lat, const float* __restrict__ w_qs,
    const float* __restrict__ w_kg, const float* __restrict__ w_vg,
    const float* __restrict__ g_w1, const float* __restrict__ g_b1,
    const float* __restrict__ g_w2, const float* __restrict__ pe_b,
    float* __restrict__ c1_out, float* __restrict__ vg_out, float* __restrict__ h2g_out)
{
    __shared__ float qs[NB][DIM];
    __shared__ float hg[NB][DIM];
    __shared__ float h1g[NB][DIM];
    int t = threadIdx.x; int b = t >> 7; int f = t & 127;
    float aq = 0.f, ak = 0.f, av = 0.f;
    for (int c = 0; c < DIM; ++c) {
        float l = lat[b*DIM + c];
        aq = fmaf(l, w_qs[c*DIM + f], aq);
        ak = fmaf(l, w_kg[c*DIM + f], ak);
        av = fmaf(l, w_vg[c*DIM + f], av);
    }
    vg_out[b*DIM + f] = av;
    qs[b][f] = aq + pe_b[f];
    hg[b][f] = aq - ak;
    __syncthreads();
    float acc = g_b1[f], acch = g_b1[f];
    for (int c = 0; c < DIM; ++c) {
        float w = g_w1[c*DIM + f];
        acc  = fmaf(qs[b][c], w, acc);
        acch = fmaf(hg[b][c], w, acch);
    }
    c1_out[b*DIM + f] = acc;
    h1g[b][f] = fmaxf(acch, 0.f);
    __syncthreads();
    float acc2 = 0.f;
    for (int c = 0; c < DIM; ++c) acc2 = fmaf(h1g[b][c], g_w2[c*DIM + f], acc2);
    h2g_out[b*DIM + f] = acc2;
}

// ---------------- K1p = points@Wk1 ; Vp' = points@w_vs + pe_b ----------------
__global__ __launch_bounds__(256) void kv_proj_k(
    const float* __restrict__ points, const float* __restrict__ Wk1,
    const float* __restrict__ w_vs, const float* __restrict__ pe_b,
    float* __restrict__ K1p, float* __restrict__ Vp)
{
    __shared__ __align__(16) float pts[KVROWS*DIM];
    int t = threadIdx.x;
    int r0 = blockIdx.x * KVROWS;
    #pragma unroll
    for (int k = 0; k < KVROWS*DIM/256; ++k) {
        int e = t + k*256;
        pts[e] = points[r0*DIM + e];
    }
    __syncthreads();
    int f = t & 127; int mat = t >> 7;
    const float* W = mat ? w_vs : Wk1;
    float* O = mat ? Vp : K1p;
    float addv = mat ? pe_b[f] : 0.f;
    float acc[KVROWS];
    #pragma unroll
    for (int r = 0; r < KVROWS; ++r) acc[r] = 0.f;
    const float4* pts4 = reinterpret_cast<const float4*>(pts);
    for (int c4 = 0; c4 < DIM/4; ++c4) {
        float w0 = W[(c4*4+0)*DIM + f];
        float w1 = W[(c4*4+1)*DIM + f];
        float w2 = W[(c4*4+2)*DIM + f];
        float w3 = W[(c4*4+3)*DIM + f];
        #pragma unroll
        for (int r = 0; r < KVROWS; ++r) {
            float4 p = pts4[r*(DIM/4) + c4];
            acc[r] = fmaf(p.x, w0, acc[r]);
            acc[r] = fmaf(p.y, w1, acc[r]);
            acc[r] = fmaf(p.z, w2, acc[r]);
            acc[r] = fmaf(p.w, w3, acc[r]);
        }
    }
    #pragma unroll
    for (int r = 0; r < KVROWS; ++r) O[(r0 + r)*DIM + f] = acc[r] + addv;
}

// ---------------- spatial binning: count / scan / scatter ----------------
__global__ __launch_bounds__(256) void cellcount_k(
    const float* __restrict__ xyz, int* __restrict__ cnt)
{
    int gid = blockIdx.x*256 + threadIdx.x;
    int b = gid >> 12; int n = gid & (NPTS - 1);
    const float* p = xyz + (b*NPTS + n)*3;
    int cx = cell_of(p[0]);
    int cy = cell_of(p[1]);
    atomicAdd(&cnt[b*NCELL + cy*GRID + cx], 1);
}

__global__ __launch_bounds__(1024) void prefix_k(
    const int* __restrict__ cnt, int* __restrict__ cell_start,
    int* __restrict__ cursor)
{
    __shared__ int s[NCELL];
    int b = blockIdx.x; int t = threadIdx.x;
    int v = cnt[b*NCELL + t];
    s[t] = v;
    __syncthreads();
    for (int off = 1; off < NCELL; off <<= 1) {
        int add = (t >= off) ? s[t - off] : 0;
        __syncthreads();
        s[t] += add;
        __syncthreads();
    }
    int incl = s[t];
    cell_start[b*(NCELL+1) + t] = incl - v;
    cursor[b*NCELL + t] = incl - v;
    if (t == NCELL - 1) cell_start[b*(NCELL+1) + NCELL] = incl;
}

__global__ __launch_bounds__(256) void scatter_k(
    const float* __restrict__ xyz, int* __restrict__ cursor,
    float2* __restrict__ sxy, int* __restrict__ sidx)
{
    int gid = blockIdx.x*256 + threadIdx.x;
    int b = gid >> 12; int n = gid & (NPTS - 1);
    const float* p = xyz + (b*NPTS + n)*3;
    float x = p[0], y = p[1];
    int cx = cell_of(x);
    int cy = cell_of(y);
    int slot = atomicAdd(&cursor[b*NCELL + cy*GRID + cx], 1);
    sxy[b*NPTS + slot] = make_float2(x, y);
    sidx[b*NPTS + slot] = n;
}

// ---------------- exact kNN: grid-binned candidates + 16x wave-argmin ----------------
__global__ __launch_bounds__(256) void knn_k(
    const float* __restrict__ xyz_q, const float2* __restrict__ sxy,
    const int* __restrict__ sidx, const int* __restrict__ cstart,
    int* __restrict__ knn_out)
{
    __shared__ float cand_d[4][CAP];
    __shared__ int   cand_i[4][CAP];
    int t = threadIdx.x; int wid = t >> 6, lane = t & 63;
    int bx = blockIdx.x; int b = bx >> 11; int q = (bx & 2047)*4 + wid;
    float xq = xyz_q[(b*NQ + q)*2 + 0];
    float yq = xyz_q[(b*NQ + q)*2 + 1];
    int cx = cell_of(xq), cy = cell_of(yq);
    const int* cs_b = cstart + b*(NCELL+1);
    float* cd = cand_d[wid]; int* ci = cand_i[wid];
    const float INF = 3.4e38f;
    const float CS = 1.0f/32.0f;
    int* outp = knn_out + (b*NQ + q)*KNN;
    int myIdx = 0;

    for (int R = 2; R < 9; ++R) {
        int x0 = max(cx-R, 0), x1 = min(cx+R, GRID-1);
        int y0 = max(cy-R, 0), y1 = min(cy+R, GRID-1);
        int cnt = 0;
        for (int ry = y0; ry <= y1; ++ry) {
            int s0 = cs_b[ry*GRID + x0];
            int e0 = cs_b[ry*GRID + x1 + 1];
            for (int o = s0 + lane; o < e0; o += 64) {
                float2 p = sxy[b*NPTS + o];
                float dx = __fadd_rn(xq, -p.x);
                float dy = __fadd_rn(yq, -p.y);
                float d = __fadd_rn(__fmul_rn(dx, dx), __fmul_rn(dy, dy));
                int slot = cnt + (o - s0);
                if (slot < CAP) { cd[slot] = d; ci[slot] = o; }
            }
            cnt += e0 - s0;
        }
        asm volatile("s_waitcnt lgkmcnt(0)" ::: "memory");
        __builtin_amdgcn_sched_barrier(0);

        float dr[6];
        #pragma unroll
        for (int k = 0; k < 6; ++k)
            dr[k] = (lane + k*64 < cnt) ? cd[lane + k*64] : INF;
        float d16 = INF;
        for (int r = 0; r < KNN; ++r) {
            float v = dr[0]; int s = lane;
            #pragma unroll
            for (int k = 1; k < 6; ++k)
                if (dr[k] < v) { v = dr[k]; s = lane + k*64; }
            #pragma unroll
            for (int off = 32; off >= 1; off >>= 1) {
                float ov = __shfl_xor(v, off);
                int   os = __shfl_xor(s, off);
                if (ov < v || (ov == v && os < s)) { v = ov; s = os; }
            }
            if (lane == r) myIdx = sidx[b*NPTS + ci[s]];
            if ((s & 63) == lane) {
                int k = s >> 6;
                if      (k == 0) dr[0] = INF;
                else if (k == 1) dr[1] = INF;
                else if (k == 2) dr[2] = INF;
                else if (k == 3) dr[3] = INF;
                else if (k == 4) dr[4] = INF;
                else             dr[5] = INF;
            }
            d16 = v;
        }
        float bl = (x0 > 0)      ? (xq - (float)x0*CS)       : INF;
        float br = (x1 < GRID-1) ? ((float)(x1+1)*CS - xq)   : INF;
        float bb = (y0 > 0)      ? (yq - (float)y0*CS)       : INF;
        float bt = (y1 < GRID-1) ? ((float)(y1+1)*CS - yq)   : INF;
        float safe = fminf(fminf(bl, br), fminf(bb, bt)) - 2e-6f;
        bool whole = (safe > 1e8f);
        bool ok = (cnt >= KNN) && (cnt <= CAP) && (whole || d16 <= safe*safe);
        if (ok || R == 8) {
            if (lane < KNN) outp[lane] = myIdx;
            break;
        }
    }
}

// ---------------- fused MFMA kernel v7: 64 KB LDS -> true 2 blocks/CU ----------------
// 512 threads = 8 waves, 1 query/wave/iter, 4 iters (32 q/block).
// pe B-frags (16 KB total) read directly from global: L1-resident broadcast,
// shared by all waves on the CU. Only w2 frags (hot, 32 KB) + h1 transpose
// buffers (32 KB) live in LDS.
__global__ __launch_bounds__(512, 2) void fuse_k(
    const float* __restrict__ xyz_q, const float* __restrict__ xyz,
    const float* __restrict__ K1p, const float* __restrict__ Vp,
    const int* __restrict__ knn_idx,
    const float* __restrict__ c1_, const float* __restrict__ vg_,
    const float* __restrict__ h2g_, const float* __restrict__ pw32_,
    const ushort_t* __restrict__ pwf, const ushort_t* __restrict__ w2f,
    float* __restrict__ out)
{
    __shared__ __align__(16) ushort_t w2B[32*512];   // 32 KB
    __shared__ __align__(16) ushort_t h1b[8][2048];  // 32 KB (single bf16, per-wave)

    int t = threadIdx.x, lane = t & 63, wid = t >> 6;
    int bx = blockIdx.x; int b = bx >> 8; int qbase = (bx & 255) * 32;

    {   // stage w2 frags once per block (32 KB)
        const int4* s2 = (const int4*)w2f;  int4* d2 = (int4*)w2B;
        #pragma unroll
        for (int i = 0; i < 4; ++i) d2[t + i*512] = s2[t + i*512];
    }
    __syncthreads();

    int c16 = lane & 15, g = lane >> 4, rowbase = g*4;
    ushort_t* hb = h1b[wid];
    const vshort8* pwBv = (const vshort8*)pwf;       // global, L1-resident
    const vshort8* w2Bv = (const vshort8*)w2B;
    const vfloat4 vzero = (vfloat4){0.f, 0.f, 0.f, 0.f};

    // query-invariant hoists (per-lane): 40 regs
    float pw32r[16], c1r[8], hgr[8], vgr[8];
    #pragma unroll
    for (int n = 0; n < 16; ++n) pw32r[n] = pw32_[n*16 + c16];
    #pragma unroll
    for (int n = 0; n < 8; ++n) {
        c1r[n] = c1_[b*128 + n*16 + c16];
        hgr[n] = h2g_[b*128 + n*16 + c16];
        vgr[n] = vg_[b*128 + n*16 + c16];
    }

    #pragma unroll 1
    for (int qi = 0; qi < 4; ++qi) {
        int q = qbase + wid*4 + qi;
        float xq = xyz_q[(b*NQ + q)*2 + 0];
        float yq = xyz_q[(b*NQ + q)*2 + 1];
        int idxrow = knn_idx[(b*NQ + q)*KNN + c16];
        const float* p = xyz + (b*NPTS + idxrow)*3;
        float pd0 = xq - p[0], pd1 = yq - p[1], pd2 = p[2];
        int idxr[4];
        #pragma unroll
        for (int r = 0; r < 4; ++r) idxr[r] = __shfl(idxrow, rowbase + r);

        // emb A-fragment in registers: k = g*8 + j
        vshort8 eh;
        int k0 = g*8;
        #pragma unroll
        for (int j = 0; j < 8; ++j) {
            int k = k0 + j;
            float v;
            if (k < 3) {
                v = (k == 0) ? pd0 : (k == 1 ? pd1 : pd2);
            } else {
                int m = k - 3; int fi = m / 6; int rem = m - fi*6;
                int comp = (rem < 3) ? rem : rem - 3;
                float pdc = (comp == 0) ? pd0 : (comp == 1 ? pd1 : pd2);
                float fr = (fi == 0) ? 1.0f : (fi == 1) ? 8.75f : (fi == 2) ? 16.5f
                         : (fi == 3) ? 24.25f : 32.0f;
                float arg = pdc * fr;
                v = (rem < 3) ? __sinf(arg) : __cosf(arg);
            }
            eh[j] = (short)bf16_rne(v);
        }
        float c32 = __cosf(32.0f * pd2);
        float c32r[4];
        #pragma unroll
        for (int r = 0; r < 4; ++r) c32r[r] = __shfl(c32, rowbase + r);

        // K1p gather prefetch (transient: dies at end of pe1 phase)
        float k1v[4][8];
        #pragma unroll
        for (int r = 0; r < 4; ++r) {
            const float* kp = K1p + ((b*NPTS + idxr[r]) << 7) + c16;
            #pragma unroll
            for (int n = 0; n < 8; ++n) k1v[r][n] = kp[n*16];
        }

        // pe1 + h1 epilogue, one n at a time (acc1 live = 4 regs)
        #pragma unroll
        for (int n = 0; n < 8; ++n) {
            vfloat4 a = __builtin_amdgcn_mfma_f32_16x16x32_bf16(
                eh, pwBv[n*64 + lane], vzero, 0, 0, 0);
            int col = n*16 + c16;
            int s = col >> 5;
            int lp = ((col >> 3) & 3) << 4;
            int j = c16 & 7;
            #pragma unroll
            for (int r = 0; r < 4; ++r) {
                float h = c1r[n] - k1v[r][n] + fmaf(c32r[r], pw32r[n], a[r]);
                h = fmaxf(h, 0.f);
                hb[s*512 + (lp | (rowbase + r))*8 + j] = bf16_rne(h);
            }
        }
        asm volatile("s_waitcnt lgkmcnt(0)" ::: "memory");
        __builtin_amdgcn_sched_barrier(0);

        // GEMM2: [16x128]@[128x128], single bf16
        vfloat4 acc2[8];
        #pragma unroll
        for (int n = 0; n < 8; ++n) acc2[n] = vzero;
        #pragma unroll
        for (int s = 0; s < 4; ++s) {
            vshort8 ah = ((const vshort8*)hb)[s*64 + lane];
            #pragma unroll
            for (int n = 0; n < 8; ++n) {
                vshort8 bh = w2Bv[(n*4 + s)*64 + lane];
                acc2[n] = __builtin_amdgcn_mfma_f32_16x16x32_bf16(ah, bh, acc2[n], 0, 0, 0);
            }
        }

        // softmax over 17 slots, pe2 computed per-n (accp live = 4 regs),
        // Vp gathers depth-1 pipelined (8 regs)
        const float* vbase[4];
        #pragma unroll
        for (int r = 0; r < 4; ++r) vbase[r] = Vp + ((b*NPTS + idxr[r]) << 7) + c16;
        float vvp[4];
        #pragma unroll
        for (int r = 0; r < 4; ++r) vvp[r] = vbase[r][0];

        #pragma unroll
        for (int n = 0; n < 8; ++n) {
            float vvc[4];
            #pragma unroll
            for (int r = 0; r < 4; ++r) vvc[r] = vvp[r];
            if (n < 7) {
                #pragma unroll
                for (int r = 0; r < 4; ++r) vvp[r] = vbase[r][(n+1)*16];
            }
            vfloat4 ap = __builtin_amdgcn_mfma_f32_16x16x32_bf16(
                eh, pwBv[(8 + n)*64 + lane], vzero, 0, 0, 0);
            #pragma unroll
            for (int r = 0; r < 4; ++r) ap[r] = fmaf(c32r[r], pw32r[8 + n], ap[r]);

            float hg = hgr[n];
            vfloat4 a2 = acc2[n];
            float mx = fmaxf(fmaxf(a2[0], a2[1]), fmaxf(a2[2], a2[3]));
            mx = fmaxf(mx, __shfl_xor(mx, 16));
            mx = fmaxf(mx, __shfl_xor(mx, 32));
            mx = fmaxf(mx, hg);
            float sum = 0.f, num = 0.f;
            #pragma unroll
            for (int r = 0; r < 4; ++r) {
                float ev = __expf(a2[r] - mx);
                float v = vvc[r] + ap[r];
                sum += ev;
                num = fmaf(ev, v, num);
            }
            sum += __shfl_xor(sum, 16); sum += __shfl_xor(sum, 32);
            num += __shfl_xor(num, 16); num += __shfl_xor(num, 32);
            float eg = __expf(hg - mx);
            sum += eg;
            num = fmaf(eg, vgr[n], num);
            if (g == 0) out[(b*NQ + q)*128 + n*16 + c16] = num / sum;
        }
        asm volatile("s_waitcnt lgkmcnt(0)" ::: "memory");
        __builtin_amdgcn_sched_barrier(0);
    }
}

extern "C" void kernel_launch(void* const* d_in, const int* in_sizes, int n_in,
                              void* d_out, int out_size, void* d_ws, size_t ws_size,
                              hipStream_t stream) {
    const float* xyz_q  = (const float*)d_in[0];
    const float* lat    = (const float*)d_in[1];
    const float* xyz    = (const float*)d_in[2];
    const float* points = (const float*)d_in[3];
    const float* w_qs   = (const float*)d_in[4];
    const float* w_ks   = (const float*)d_in[5];
    const float* w_vs   = (const float*)d_in[6];
    const float* w_kg   = (const float*)d_in[7];
    const float* w_vg   = (const float*)d_in[8];
    const float* g_w1   = (const float*)d_in[9];
    const float* g_b1   = (const float*)d_in[10];
    const float* g_w2   = (const float*)d_in[11];
    const float* g_b2   = (const float*)d_in[12];  // cancels under softmax
    const float* pe_w   = (const float*)d_in[13];
    const float* pe_b   = (const float*)d_in[14];
    float* out = (float*)d_out;
    (void)g_b2;

    float* ws   = (float*)d_ws;
    float* Vp   = ws;                          // 2*4096*128
    float* K1p  = Vp  + NB*NPTS*DIM;           // 2*4096*128
    float* Wk1  = K1p + NB*NPTS*DIM;           // 128*128
    float* pwc  = Wk1 + DIM*DIM;               // 64*256
    float* c1   = pwc + 64*256;                // 256
    float* vg   = c1  + NB*DIM;                // 256
    float* h2g  = vg  + NB*DIM;                // 256
    int*   knn  = (int*)(h2g + NB*DIM);        // 2*8192*16
    ushort_t* pwf = (ushort_t*)(knn + NB*NQ*KNN);   // 16 KB
    ushort_t* w2f = pwf + 16*64*8;                  // 32 KB
    int* cellcnt  = (int*)(w2f + 32*64*8);          // 2*1024
    int* cellstart = cellcnt + NB*NCELL;            // 2*1025
    int* cursor    = cellstart + NB*(NCELL+1);      // 2*1024
    int* sidx      = cursor + NB*NCELL;             // 2*4096
    float2* sxy    = (float2*)(sidx + NB*NPTS);     // 2*4096 float2

    hipMemsetAsync(cellcnt, 0, NB*NCELL*sizeof(int), stream);
    wprod_k<<<192, 128, 0, stream>>>(w_ks, g_w1, pe_w, Wk1, pwc);
    pack_k<<<4, 256, 0, stream>>>(pwc, 32, 256, 16, 1, pwf);
    pack_k<<<8, 256, 0, stream>>>(g_w2, 128, 128, 8, 4, w2f);
    prep_global_k<<<1, 256, 0, stream>>>(lat, w_qs, w_kg, w_vg,
                                         g_w1, g_b1, g_w2, pe_b, c1, vg, h2g);
    cellcount_k<<<NB*NPTS/256, 256, 0, stream>>>(xyz, cellcnt);
    prefix_k<<<NB, 1024, 0, stream>>>(cellcnt, cellstart, cursor);
    scatter_k<<<NB*NPTS/256, 256, 0, stream>>>(xyz, cursor, sxy, sidx);
    kv_proj_k<<<NB*NPTS/KVROWS, 256, 0, stream>>>(points, Wk1, w_vs, pe_b, K1p, Vp);
    knn_k<<<NB*NQ/4, 256, 0, stream>>>(xyz_q, sxy, sidx, cellstart, knn);
    fuse_k<<<NB*NQ/32, 512, 0, stream>>>(xyz_q, xyz, K1p, Vp, knn, c1, vg, h2g,
                                         pwc + 32*256, pwf, w2f, out);
}